// Round 13
// baseline (184.714 us; speedup 1.0000x reference)
//
#include <hip/hip_runtime.h>

#define NDIM 128
#define NBKT 512      // dst buckets for CSR build
#define NWPART 128    // partition workgroups

typedef __attribute__((ext_vector_type(8))) short s8v;   // 8 bf16 in 4 VGPRs
typedef __attribute__((ext_vector_type(4))) float f4v;   // MFMA accumulator

__device__ inline unsigned short f2bf_rne(float x) {
    unsigned u = __float_as_uint(x);
    unsigned r = u + 0x7FFFu + ((u >> 16) & 1u);
    return (unsigned short)(r >> 16);
}
__device__ inline float bf2f(unsigned short b) {
    return __uint_as_float(((unsigned)b) << 16);
}

// ---------------- per-node attention projections, 16-lane group per node
__global__ __launch_bounds__(256) void k_proj(const float* __restrict__ h,
                                              const float* __restrict__ Wa1,
                                              const float* __restrict__ Wa2,
                                              const float* __restrict__ Wa3,
                                              float* __restrict__ proj, int N)
{
    int tid = threadIdx.x;
    int l   = tid & 15;
    int n   = blockIdx.x * 16 + (tid >> 4);
    if (n >= N) return;
    int o = l * 8;
    float4 w1s0 = *(const float4*)(Wa1 + o),       w1s1 = *(const float4*)(Wa1 + o + 4);
    float4 w1d0 = *(const float4*)(Wa1 + 128 + o), w1d1 = *(const float4*)(Wa1 + 132 + o);
    float4 w2s0 = *(const float4*)(Wa2 + o),       w2s1 = *(const float4*)(Wa2 + o + 4);
    float4 w2d0 = *(const float4*)(Wa2 + 128 + o), w2d1 = *(const float4*)(Wa2 + 132 + o);
    float4 w3s0 = *(const float4*)(Wa3 + o),       w3s1 = *(const float4*)(Wa3 + o + 4);
    float4 w3d0 = *(const float4*)(Wa3 + 128 + o), w3d1 = *(const float4*)(Wa3 + 132 + o);
    float4 x0 = *(const float4*)(h + (size_t)n * NDIM + o);
    float4 x1 = *(const float4*)(h + (size_t)n * NDIM + o + 4);
    float s1 = x0.x*w1s0.x + x0.y*w1s0.y + x0.z*w1s0.z + x0.w*w1s0.w
             + x1.x*w1s1.x + x1.y*w1s1.y + x1.z*w1s1.z + x1.w*w1s1.w;
    float s2 = x0.x*w2s0.x + x0.y*w2s0.y + x0.z*w2s0.z + x0.w*w2s0.w
             + x1.x*w2s1.x + x1.y*w2s1.y + x1.z*w2s1.z + x1.w*w2s1.w;
    float s3 = x0.x*w3s0.x + x0.y*w3s0.y + x0.z*w3s0.z + x0.w*w3s0.w
             + x1.x*w3s1.x + x1.y*w3s1.y + x1.z*w3s1.z + x1.w*w3s1.w;
    float d1 = x0.x*w1d0.x + x0.y*w1d0.y + x0.z*w1d0.z + x0.w*w1d0.w
             + x1.x*w1d1.x + x1.y*w1d1.y + x1.z*w1d1.z + x1.w*w1d1.w;
    float d2 = x0.x*w2d0.x + x0.y*w2d0.y + x0.z*w2d0.z + x0.w*w2d0.w
             + x1.x*w2d1.x + x1.y*w2d1.y + x1.z*w2d1.z + x1.w*w2d1.w;
    float d3 = x0.x*w3d0.x + x0.y*w3d0.y + x0.z*w3d0.z + x0.w*w3d0.w
             + x1.x*w3d1.x + x1.y*w3d1.y + x1.z*w3d1.z + x1.w*w3d1.w;
#pragma unroll
    for (int m = 1; m < 16; m <<= 1) {
        s1 += __shfl_xor(s1, m);
        s2 += __shfl_xor(s2, m);
        s3 += __shfl_xor(s3, m);
        d1 += __shfl_xor(d1, m);
        d2 += __shfl_xor(d2, m);
        d3 += __shfl_xor(d3, m);
    }
    if (l == 0) {
        *(float4*)(proj + (size_t)n * 8)     = make_float4(s1, s2, s3, 0.f);
        *(float4*)(proj + (size_t)n * 8 + 4) = make_float4(d1, d2, d3, 0.f);
    }
}

// ---------------- partition pass 1: per-(wg,bucket) histogram (LDS atomics only)
__global__ __launch_bounds__(256) void k_part1(const int* __restrict__ dst,
                                               int* __restrict__ hist, int E, int npb)
{
    __shared__ int lh[NBKT];
    int w = blockIdx.x, NW = gridDim.x;
    for (int i = threadIdx.x; i < NBKT; i += 256) lh[i] = 0;
    __syncthreads();
    int per = (E + NW - 1) / NW;
    int e0 = w * per, e1 = min(E, e0 + per);
    for (int e = e0 + threadIdx.x; e < e1; e += 256)
        atomicAdd(&lh[dst[e] / npb], 1);
    __syncthreads();
    for (int b = threadIdx.x; b < NBKT; b += 256)
        hist[b * NW + w] = lh[b];
}

// ---------------- partition scan, parallelized
__global__ __launch_bounds__(NWPART) void k_pscan_a(int* __restrict__ hist,
                                                    int* __restrict__ tot)
{
    __shared__ int s[NWPART];
    int b = blockIdx.x, t = threadIdx.x;
    int v = hist[b * NWPART + t];
    s[t] = v;
    __syncthreads();
    for (int d = 1; d < NWPART; d <<= 1) {
        int u = (t >= d) ? s[t - d] : 0;
        __syncthreads();
        s[t] += u;
        __syncthreads();
    }
    hist[b * NWPART + t] = s[t] - v;
    if (t == NWPART - 1) tot[b] = s[NWPART - 1];
}

__global__ __launch_bounds__(NBKT) void k_pscan_b(const int* __restrict__ tot,
                                                  int* __restrict__ bbase, int E)
{
    __shared__ int s[NBKT];
    int b = threadIdx.x;
    int v = tot[b];
    s[b] = v;
    __syncthreads();
    for (int d = 1; d < NBKT; d <<= 1) {
        int u = (b >= d) ? s[b - d] : 0;
        __syncthreads();
        s[b] += u;
        __syncthreads();
    }
    bbase[b] = s[b] - v;
    if (b == NBKT - 1) bbase[NBKT] = E;
}

// ---------------- partition pass 2 (+ bucket-base add): scatter packed records
__global__ __launch_bounds__(256) void k_part2(const int* __restrict__ src,
                                               const int* __restrict__ dst,
                                               const int* __restrict__ hist,
                                               const int* __restrict__ bbase,
                                               unsigned* __restrict__ ebuf, int E, int npb)
{
    __shared__ int cur[NBKT];
    int w = blockIdx.x, NW = gridDim.x;
    for (int i = threadIdx.x; i < NBKT; i += 256)
        cur[i] = hist[i * NW + w] + bbase[i];
    __syncthreads();
    int per = (E + NW - 1) / NW;
    int e0 = w * per, e1 = min(E, e0 + per);
    for (int e = e0 + threadIdx.x; e < e1; e += 256) {
        int d = dst[e], b = d / npb;
        int pos = atomicAdd(&cur[b], 1);
        ebuf[pos] = ((unsigned)src[e] << 7) | (unsigned)(d - b * npb);
    }
}

// ---------------- fused per-bucket: degree count -> LDS scan -> offs -> perm scatter
__global__ __launch_bounds__(256) void k_bucket(const unsigned* __restrict__ ebuf,
                                                const int* __restrict__ bbase,
                                                int* __restrict__ offs,
                                                int* __restrict__ perm,
                                                int N, int npb, int E)
{
    __shared__ int lc[128];
    __shared__ int ls[128];
    int b   = blockIdx.x;
    int tid = threadIdx.x;
    for (int i = tid; i < 128; i += 256) lc[i] = 0;
    __syncthreads();
    int e0 = bbase[b], e1 = bbase[b + 1];
    for (int e = e0 + tid; e < e1; e += 256)
        atomicAdd(&lc[ebuf[e] & 127], 1);
    __syncthreads();
    if (tid < 128) ls[tid] = lc[tid];
    __syncthreads();
    for (int d = 1; d < 128; d <<= 1) {
        int u = (tid < 128 && tid >= d) ? ls[tid - d] : 0;
        __syncthreads();
        if (tid < 128) ls[tid] += u;
        __syncthreads();
    }
    int n0 = b * npb;
    if (tid < 128) {
        int excl = ls[tid] - lc[tid] + e0;
        if (tid < npb && n0 + tid < N) offs[n0 + tid] = excl;
        lc[tid] = excl;
    }
    if (b == 0 && tid == 0) offs[N] = E;
    __syncthreads();
    for (int e = e0 + tid; e < e1; e += 256) {
        unsigned r = ebuf[e];
        int pos = atomicAdd(&lc[r & 127], 1);
        perm[pos] = (int)(r >> 7);
    }
}

// ---------------- per-dst-node aggregation, 16-lane group per node (4 nodes/wave)
__global__ __launch_bounds__(256) void k_aggr(const unsigned short* __restrict__ msgb,
                                              const float* __restrict__ proj,
                                              const int* __restrict__ offs,
                                              const int* __restrict__ perm,
                                              const float* __restrict__ ba1,
                                              const float* __restrict__ ba2,
                                              const float* __restrict__ ba3,
                                              unsigned short* __restrict__ hneigh, int N)
{
    int tid  = threadIdx.x;
    int lane = tid & 63;
    int l    = lane & 15;
    int g    = lane >> 4;
    int wvid = blockIdx.x * (blockDim.x >> 6) + (tid >> 6);
    int n    = wvid * 4 + g;
    bool alive = (n < N);

    int o0 = 0, o1 = 0;
    float dd1 = 0.f, dd2 = 0.f, dd3 = 0.f;
    if (alive) {
        o0 = offs[n];
        o1 = offs[n + 1];
        dd1 = proj[(size_t)n * 8 + 4];
        dd2 = proj[(size_t)n * 8 + 5];
        dd3 = proj[(size_t)n * 8 + 6];
    }
    int deg = o1 - o0;
    float b1 = ba1[0], b2 = ba2[0], b3 = ba3[0];

    int   m0 = min(deg, 16);
    int   sc = 0;
    float a1c = 0.f, a2c = 0.f, a3c = 0.f;
    if (l < m0) {
        sc = perm[o0 + l];
        float4 sp = *(const float4*)(proj + (size_t)sc * 8);
        a1c = __expf(fmaxf(sp.x + dd1 + b1, 0.f));
        a2c = __expf(fmaxf(sp.y + dd2 + b2, 0.f));
        a3c = __expf(fmaxf(sp.z + dd3 + b3, 0.f));
    }
    float s1 = a1c, s2 = a2c, s3 = a3c;
    for (int i = o0 + 16 + l; i < o1; i += 16) {
        int s = perm[i];
        float4 sp = *(const float4*)(proj + (size_t)s * 8);
        s1 += __expf(fmaxf(sp.x + dd1 + b1, 0.f));
        s2 += __expf(fmaxf(sp.y + dd2 + b2, 0.f));
        s3 += __expf(fmaxf(sp.z + dd3 + b3, 0.f));
    }
#pragma unroll
    for (int m = 1; m < 16; m <<= 1) {
        s1 += __shfl_xor(s1, m);
        s2 += __shfl_xor(s2, m);
        s3 += __shfl_xor(s3, m);
    }
    float r1 = 1.f / s1, r2 = 1.f / s2, r3 = 1.f / s3;

    float acc[8] = {};
    int gbase = g << 4;
    {
        float wv = (a1c * r1 + a2c * r2 + a3c * r3) * (1.f / 3.f);
        for (int j = 0; j < m0; ++j) {
            int   s = __shfl(sc, gbase + j);
            float w = __shfl(wv, gbase + j);
            s8v v = *(const s8v*)(msgb + (size_t)s * NDIM + l * 8);
#pragma unroll
            for (int k = 0; k < 8; ++k)
                acc[k] += w * bf2f((unsigned short)v[k]);
        }
    }
    for (int base = o0 + 16; base < o1; base += 16) {
        int m  = min(16, o1 - base);
        int sv = 0;
        float wv = 0.f;
        if (l < m) {
            sv = perm[base + l];
            float4 sp = *(const float4*)(proj + (size_t)sv * 8);
            float a1 = __expf(fmaxf(sp.x + dd1 + b1, 0.f));
            float a2 = __expf(fmaxf(sp.y + dd2 + b2, 0.f));
            float a3 = __expf(fmaxf(sp.z + dd3 + b3, 0.f));
            wv = (a1 * r1 + a2 * r2 + a3 * r3) * (1.f / 3.f);
        }
        for (int j = 0; j < m; ++j) {
            int   s = __shfl(sv, gbase + j);
            float w = __shfl(wv, gbase + j);
            s8v v = *(const s8v*)(msgb + (size_t)s * NDIM + l * 8);
#pragma unroll
            for (int k = 0; k < 8; ++k)
                acc[k] += w * bf2f((unsigned short)v[k]);
        }
    }
    if (alive) {
        float inv = (deg > 0) ? 1.f / (float)deg : 0.f;
        s8v hv;
#pragma unroll
        for (int k = 0; k < 8; ++k)
            hv[k] = (short)f2bf_rne(acc[k] * inv);
        *(s8v*)(hneigh + (size_t)n * NDIM + l * 8) = hv;
    }
}

// ---------------- weight convert: W[k][c] fp32 -> bf16 hi/lo planes in MFMA
// B-FRAGMENT ORDER: offset = plane*16384 + ((ct*4+ks)*64 + lane)*8 + j
__global__ void k_cvt_w(const float* __restrict__ w0, const float* __restrict__ w1,
                        const float* __restrict__ w2, const float* __restrict__ w3,
                        const float* __restrict__ w4, const float* __restrict__ w5,
                        unsigned short* __restrict__ out)
{
    const float* srcs[6] = {w0, w1, w2, w3, w4, w5};
    const float* W = srcs[blockIdx.y];
    int idx  = blockIdx.x * 256 + threadIdx.x;   // 0..16383
    int j    = idx & 7;
    int lane = (idx >> 3) & 63;
    int ks   = (idx >> 9) & 3;
    int ct   = idx >> 11;
    int col  = ct * 16 + (lane & 15);
    int k    = ks * 32 + (lane >> 4) * 8 + j;
    float x = W[k * 128 + col];
    unsigned xb = __float_as_uint(x);
    float hf = __uint_as_float(xb & 0xFFFF0000u);
    float rr = x - hf;
    unsigned short hi = (unsigned short)(xb >> 16);
    unsigned short lo = (unsigned short)(__float_as_uint(rr) >> 16);
    unsigned short* ob = out + (size_t)blockIdx.y * 32768;
    ob[idx] = hi;
    ob[16384 + idx] = lo;
}

// ======== barrier-free wave-tile GEMM helpers: one WAVE owns a 16-row x 128-col
// tile; activations live in a wave-private 4 KB LDS slice (within-wave ordering
// only, no __syncthreads). Weights read per-MFMA from L2 (fragment-ordered).

// fp32 A pass (split hi/lo): 96 MFMA into acc[8]
__device__ inline void wv_mfma_f32(const float* __restrict__ A, int N, int wrow0,
                                   int ln, int g, int lane,
                                   const unsigned short* __restrict__ wf, f4v acc[8])
{
    int rA = min(wrow0 + ln, N - 1);
#pragma unroll
    for (int ks = 0; ks < 4; ++ks) {
        const float* ar = A + (size_t)rA * 128 + ks * 32 + g * 8;
        float4 x0 = *(const float4*)(ar);
        float4 x1 = *(const float4*)(ar + 4);
        float xs[8] = {x0.x, x0.y, x0.z, x0.w, x1.x, x1.y, x1.z, x1.w};
        s8v ahi, alo;
#pragma unroll
        for (int j = 0; j < 8; ++j) {
            unsigned xb = __float_as_uint(xs[j]);
            float hf = __uint_as_float(xb & 0xFFFF0000u);
            float rr = xs[j] - hf;
            ahi[j] = (short)(xb >> 16);
            alo[j] = (short)(__float_as_uint(rr) >> 16);
        }
#pragma unroll
        for (int ct = 0; ct < 8; ++ct) {
            const unsigned short* p = wf + ((((ct << 2) + ks) * 64) + lane) * 8;
            s8v wh = *(const s8v*)p;
            s8v wl = *(const s8v*)(p + 16384);
            acc[ct] = __builtin_amdgcn_mfma_f32_16x16x32_bf16(ahi, wh, acc[ct], 0, 0, 0);
            acc[ct] = __builtin_amdgcn_mfma_f32_16x16x32_bf16(alo, wh, acc[ct], 0, 0, 0);
            acc[ct] = __builtin_amdgcn_mfma_f32_16x16x32_bf16(ahi, wl, acc[ct], 0, 0, 0);
        }
    }
}

// bf16 global A pass: 64 MFMA into acc[8]
__device__ inline void wv_mfma_bf16g(const unsigned short* __restrict__ A, int N, int wrow0,
                                     int ln, int g, int lane,
                                     const unsigned short* __restrict__ wf, f4v acc[8])
{
    int rA = min(wrow0 + ln, N - 1);
#pragma unroll
    for (int ks = 0; ks < 4; ++ks) {
        s8v a = *(const s8v*)(A + (size_t)rA * 128 + ks * 32 + g * 8);
#pragma unroll
        for (int ct = 0; ct < 8; ++ct) {
            const unsigned short* p = wf + ((((ct << 2) + ks) * 64) + lane) * 8;
            s8v wh = *(const s8v*)p;
            s8v wl = *(const s8v*)(p + 16384);
            acc[ct] = __builtin_amdgcn_mfma_f32_16x16x32_bf16(a, wh, acc[ct], 0, 0, 0);
            acc[ct] = __builtin_amdgcn_mfma_f32_16x16x32_bf16(a, wl, acc[ct], 0, 0, 0);
        }
    }
}

// bf16 LDS A pass (wave-private slice): 64 MFMA into acc[8]
__device__ inline void wv_mfma_lds(const unsigned short* __restrict__ act,
                                   int ln, int g, int lane,
                                   const unsigned short* __restrict__ wf, f4v acc[8])
{
#pragma unroll
    for (int ks = 0; ks < 4; ++ks) {
        s8v a = *(const s8v*)(&act[(ln * 128 + ks * 32 + g * 8) ^ ((ln & 7) << 3)]);
#pragma unroll
        for (int ct = 0; ct < 8; ++ct) {
            const unsigned short* p = wf + ((((ct << 2) + ks) * 64) + lane) * 8;
            s8v wh = *(const s8v*)p;
            s8v wl = *(const s8v*)(p + 16384);
            acc[ct] = __builtin_amdgcn_mfma_f32_16x16x32_bf16(a, wh, acc[ct], 0, 0, 0);
            acc[ct] = __builtin_amdgcn_mfma_f32_16x16x32_bf16(a, wl, acc[ct], 0, 0, 0);
        }
    }
}

// bias + relu + bf16 round -> wave-private swizzled act LDS; zeros acc.
// C/D: row = g*4+q (within 16-row tile), col = ct*16+ln.
__device__ inline void wv_write_act(f4v acc[8], const float* __restrict__ bias,
                                    unsigned short* __restrict__ act, int ln, int g)
{
#pragma unroll
    for (int ct = 0; ct < 8; ++ct) {
        int col = ct * 16 + ln;
        float bv = bias[col];
#pragma unroll
        for (int q = 0; q < 4; ++q) {
            int row = g * 4 + q;
            float o = fmaxf(acc[ct][q] + bv, 0.f);
            act[(row * 128 + col) ^ ((row & 7) << 3)] = f2bf_rne(o);
            acc[ct][q] = 0.f;
        }
    }
}

// ---------------- fused 3-layer message MLP, barrier-free (1 wave = 16 rows)
__global__ __launch_bounds__(256, 4) void k_mlp3(const float* __restrict__ h,
                                                 const unsigned short* __restrict__ w1,
                                                 const unsigned short* __restrict__ w2,
                                                 const unsigned short* __restrict__ w3,
                                                 const float* __restrict__ b1,
                                                 const float* __restrict__ b2,
                                                 const float* __restrict__ b3,
                                                 unsigned short* __restrict__ msg, int N)
{
    __shared__ unsigned short acts[4][2048];   // 4 KB per wave
    int tid  = threadIdx.x;
    int lane = tid & 63;
    int wid  = tid >> 6;
    int ln   = lane & 15;
    int g    = lane >> 4;
    int wt   = blockIdx.x * 4 + wid;           // wave-tile id
    int nT   = (N + 15) / 16;
    if (wt >= nT) return;                      // legal: no barriers in this kernel
    int wrow0 = wt * 16;
    unsigned short* act = acts[wid];

    f4v acc[8] = {};
    wv_mfma_f32(h, N, wrow0, ln, g, lane, w1, acc);
    wv_write_act(acc, b1, act, ln, g);
    wv_mfma_lds(act, ln, g, lane, w2, acc);
    wv_write_act(acc, b2, act, ln, g);
    wv_mfma_lds(act, ln, g, lane, w3, acc);
    wv_write_act(acc, b3, act, ln, g);
    // coalesced copyout: lane covers row = lane>>2, cols (lane&3)*32..+32
    {
        int row  = lane >> 2;
        int c0   = (lane & 3) * 32;
        int grow = wrow0 + row;
        if (grow < N) {
#pragma unroll
            for (int t = 0; t < 4; ++t) {
                int c = c0 + t * 8;
                s8v v = *(const s8v*)(&act[(row * 128 + c) ^ ((row & 7) << 3)]);
                *(s8v*)(msg + (size_t)grow * 128 + c) = v;
            }
        }
    }
}

// ---------------- fused head, barrier-free (1 wave = 16 rows)
__global__ __launch_bounds__(256, 4) void k_head(const float* __restrict__ h,
                                                 const unsigned short* __restrict__ hneigh,
                                                 const unsigned short* __restrict__ wc1a,
                                                 const unsigned short* __restrict__ wc1b,
                                                 const unsigned short* __restrict__ wc2,
                                                 const float* __restrict__ bc1,
                                                 const float* __restrict__ bc2,
                                                 float* __restrict__ out, int N)
{
    __shared__ unsigned short acts[4][2048];
    int tid  = threadIdx.x;
    int lane = tid & 63;
    int wid  = tid >> 6;
    int ln   = lane & 15;
    int g    = lane >> 4;
    int wt   = blockIdx.x * 4 + wid;
    int nT   = (N + 15) / 16;
    if (wt >= nT) return;
    int wrow0 = wt * 16;
    unsigned short* act = acts[wid];

    f4v acc[8] = {};
    wv_mfma_f32(h, N, wrow0, ln, g, lane, wc1a, acc);
    wv_mfma_bf16g(hneigh, N, wrow0, ln, g, lane, wc1b, acc);
    wv_write_act(acc, bc1, act, ln, g);
    wv_mfma_lds(act, ln, g, lane, wc2, acc);
    // epilogue: fp32 global store (row = g*4+q, col = ct*16+ln)
#pragma unroll
    for (int ct = 0; ct < 8; ++ct) {
        int col = ct * 16 + ln;
        float bv = bc2[col];
#pragma unroll
        for (int q = 0; q < 4; ++q) {
            int orow = wrow0 + g * 4 + q;
            if (orow < N)
                out[(size_t)orow * 128 + col] = acc[ct][q] + bv;
        }
    }
}

extern "C" void kernel_launch(void* const* d_in, const int* in_sizes, int n_in,
                              void* d_out, int out_size, void* d_ws, size_t ws_size,
                              hipStream_t stream)
{
    const float* h   = (const float*)d_in[0];
    const int*   src = (const int*)d_in[1];
    const int*   dst = (const int*)d_in[2];
    const float* Wm1 = (const float*)d_in[3];
    const float* bm1 = (const float*)d_in[4];
    const float* Wm2 = (const float*)d_in[5];
    const float* bm2 = (const float*)d_in[6];
    const float* Wm3 = (const float*)d_in[7];
    const float* bm3 = (const float*)d_in[8];
    const float* Wa1 = (const float*)d_in[9];
    const float* ba1 = (const float*)d_in[10];
    const float* Wa2 = (const float*)d_in[11];
    const float* ba2 = (const float*)d_in[12];
    const float* Wa3 = (const float*)d_in[13];
    const float* ba3 = (const float*)d_in[14];
    const float* Wc1 = (const float*)d_in[15];
    const float* bc1 = (const float*)d_in[16];
    const float* Wc2 = (const float*)d_in[17];
    const float* bc2 = (const float*)d_in[18];

    const int N = in_sizes[0] / NDIM;
    const int E = in_sizes[1];
    const int npb = (N + NBKT - 1) / NBKT;
    float* out = (float*)d_out;

    // workspace layout
    unsigned short* wt  = (unsigned short*)d_ws;                 // 6*32768 ushorts
    unsigned short* mb1 = wt + 6 * 32768;                        // N*128 bf16 (hneigh)
    unsigned short* mb2 = mb1 + (size_t)N * NDIM;                // N*128 bf16 (msg)
    float* proj = (float*)(mb2 + (size_t)N * NDIM);              // N*8
    int* offs   = (int*)(proj + (size_t)N * 8);                  // N+1
    int* hist   = offs + N + 1;                                  // NBKT*NWPART
    int* bbase  = hist + NBKT * NWPART;                          // NBKT+1
    int* btot   = bbase + NBKT + 1;                              // NBKT
    unsigned* ebuf = (unsigned*)(btot + NBKT);                   // E
    int* perm   = (int*)(ebuf + E);                              // E

    const unsigned short* wt_m1  = wt;
    const unsigned short* wt_m2  = wt + 1 * 32768;
    const unsigned short* wt_m3  = wt + 2 * 32768;
    const unsigned short* wt_c1a = wt + 3 * 32768;
    const unsigned short* wt_c1b = wt + 4 * 32768;
    const unsigned short* wt_c2  = wt + 5 * 32768;

    k_cvt_w<<<dim3(64, 6), 256, 0, stream>>>(Wm1, Wm2, Wm3, Wc1, Wc1 + 128 * 128, Wc2, wt);
    k_proj<<<(N + 15) / 16, 256, 0, stream>>>(h, Wa1, Wa2, Wa3, proj, N);

    // ---- bucketed CSR build
    k_part1<<<NWPART, 256, 0, stream>>>(dst, hist, E, npb);
    k_pscan_a<<<NBKT, NWPART, 0, stream>>>(hist, btot);
    k_pscan_b<<<1, NBKT, 0, stream>>>(btot, bbase, E);
    k_part2<<<NWPART, 256, 0, stream>>>(src, dst, hist, bbase, ebuf, E, npb);
    k_bucket<<<NBKT, 256, 0, stream>>>(ebuf, bbase, offs, perm, N, npb, E);

    int nT = (N + 15) / 16;          // wave-tiles
    int gb = (nT + 3) / 4;           // 4 waves per 256-thread block
    // fused 3-layer message MLP -> msg (mb2)
    k_mlp3<<<gb, 256, 0, stream>>>(h, wt_m1, wt_m2, wt_m3, bm1, bm2, bm3, mb2, N);

    // aggregation -> hneigh (mb1)
    int nwaves = (N + 3) / 4;
    int nblk   = (nwaves + 3) / 4;
    k_aggr<<<nblk, 256, 0, stream>>>(mb2, proj, offs, perm, ba1, ba2, ba3, mb1, N);

    // fused head -> out
    k_head<<<gb, 256, 0, stream>>>(h, mb1, wt_c1a, wt_c1b, wt_c2, bc1, bc2, out, N);
}

// Round 14
// 140.846 us; speedup vs baseline: 1.3115x; 1.3115x over previous
//
#include <hip/hip_runtime.h>

#define NDIM 128
#define NBKT 512      // dst buckets for CSR build
#define NWPART 128    // partition workgroups

typedef __attribute__((ext_vector_type(8))) short s8v;   // 8 bf16 in 4 VGPRs
typedef __attribute__((ext_vector_type(4))) float f4v;   // MFMA accumulator

__device__ inline unsigned short f2bf_rne(float x) {
    unsigned u = __float_as_uint(x);
    unsigned r = u + 0x7FFFu + ((u >> 16) & 1u);
    return (unsigned short)(r >> 16);
}
__device__ inline float bf2f(unsigned short b) {
    return __uint_as_float(((unsigned)b) << 16);
}

// ---------------- per-node attention projections + bf16 cast of h
__global__ __launch_bounds__(256) void k_proj(const float* __restrict__ h,
                                              const float* __restrict__ Wa1,
                                              const float* __restrict__ Wa2,
                                              const float* __restrict__ Wa3,
                                              float* __restrict__ proj,
                                              unsigned short* __restrict__ hb, int N)
{
    int tid = threadIdx.x;
    int l   = tid & 15;
    int n   = blockIdx.x * 16 + (tid >> 4);
    if (n >= N) return;
    int o = l * 8;
    float4 w1s0 = *(const float4*)(Wa1 + o),       w1s1 = *(const float4*)(Wa1 + o + 4);
    float4 w1d0 = *(const float4*)(Wa1 + 128 + o), w1d1 = *(const float4*)(Wa1 + 132 + o);
    float4 w2s0 = *(const float4*)(Wa2 + o),       w2s1 = *(const float4*)(Wa2 + o + 4);
    float4 w2d0 = *(const float4*)(Wa2 + 128 + o), w2d1 = *(const float4*)(Wa2 + 132 + o);
    float4 w3s0 = *(const float4*)(Wa3 + o),       w3s1 = *(const float4*)(Wa3 + o + 4);
    float4 w3d0 = *(const float4*)(Wa3 + 128 + o), w3d1 = *(const float4*)(Wa3 + 132 + o);
    float4 x0 = *(const float4*)(h + (size_t)n * NDIM + o);
    float4 x1 = *(const float4*)(h + (size_t)n * NDIM + o + 4);
    // bf16 copy of h (each lane owns 8 contiguous cols; 16 lanes = 256B/node)
    {
        s8v hv;
        hv[0] = (short)f2bf_rne(x0.x); hv[1] = (short)f2bf_rne(x0.y);
        hv[2] = (short)f2bf_rne(x0.z); hv[3] = (short)f2bf_rne(x0.w);
        hv[4] = (short)f2bf_rne(x1.x); hv[5] = (short)f2bf_rne(x1.y);
        hv[6] = (short)f2bf_rne(x1.z); hv[7] = (short)f2bf_rne(x1.w);
        *(s8v*)(hb + (size_t)n * NDIM + o) = hv;
    }
    float s1 = x0.x*w1s0.x + x0.y*w1s0.y + x0.z*w1s0.z + x0.w*w1s0.w
             + x1.x*w1s1.x + x1.y*w1s1.y + x1.z*w1s1.z + x1.w*w1s1.w;
    float s2 = x0.x*w2s0.x + x0.y*w2s0.y + x0.z*w2s0.z + x0.w*w2s0.w
             + x1.x*w2s1.x + x1.y*w2s1.y + x1.z*w2s1.z + x1.w*w2s1.w;
    float s3 = x0.x*w3s0.x + x0.y*w3s0.y + x0.z*w3s0.z + x0.w*w3s0.w
             + x1.x*w3s1.x + x1.y*w3s1.y + x1.z*w3s1.z + x1.w*w3s1.w;
    float d1 = x0.x*w1d0.x + x0.y*w1d0.y + x0.z*w1d0.z + x0.w*w1d0.w
             + x1.x*w1d1.x + x1.y*w1d1.y + x1.z*w1d1.z + x1.w*w1d1.w;
    float d2 = x0.x*w2d0.x + x0.y*w2d0.y + x0.z*w2d0.z + x0.w*w2d0.w
             + x1.x*w2d1.x + x1.y*w2d1.y + x1.z*w2d1.z + x1.w*w2d1.w;
    float d3 = x0.x*w3d0.x + x0.y*w3d0.y + x0.z*w3d0.z + x0.w*w3d0.w
             + x1.x*w3d1.x + x1.y*w3d1.y + x1.z*w3d1.z + x1.w*w3d1.w;
#pragma unroll
    for (int m = 1; m < 16; m <<= 1) {
        s1 += __shfl_xor(s1, m);
        s2 += __shfl_xor(s2, m);
        s3 += __shfl_xor(s3, m);
        d1 += __shfl_xor(d1, m);
        d2 += __shfl_xor(d2, m);
        d3 += __shfl_xor(d3, m);
    }
    if (l == 0) {
        *(float4*)(proj + (size_t)n * 8)     = make_float4(s1, s2, s3, 0.f);
        *(float4*)(proj + (size_t)n * 8 + 4) = make_float4(d1, d2, d3, 0.f);
    }
}

// ---------------- partition pass 1: per-(wg,bucket) histogram (LDS atomics only)
__global__ __launch_bounds__(256) void k_part1(const int* __restrict__ dst,
                                               int* __restrict__ hist, int E, int npb)
{
    __shared__ int lh[NBKT];
    int w = blockIdx.x, NW = gridDim.x;
    for (int i = threadIdx.x; i < NBKT; i += 256) lh[i] = 0;
    __syncthreads();
    int per = (E + NW - 1) / NW;
    int e0 = w * per, e1 = min(E, e0 + per);
    for (int e = e0 + threadIdx.x; e < e1; e += 256)
        atomicAdd(&lh[dst[e] / npb], 1);
    __syncthreads();
    for (int b = threadIdx.x; b < NBKT; b += 256)
        hist[b * NW + w] = lh[b];
}

// ---------------- partition scan, parallelized
__global__ __launch_bounds__(NWPART) void k_pscan_a(int* __restrict__ hist,
                                                    int* __restrict__ tot)
{
    __shared__ int s[NWPART];
    int b = blockIdx.x, t = threadIdx.x;
    int v = hist[b * NWPART + t];
    s[t] = v;
    __syncthreads();
    for (int d = 1; d < NWPART; d <<= 1) {
        int u = (t >= d) ? s[t - d] : 0;
        __syncthreads();
        s[t] += u;
        __syncthreads();
    }
    hist[b * NWPART + t] = s[t] - v;
    if (t == NWPART - 1) tot[b] = s[NWPART - 1];
}

__global__ __launch_bounds__(NBKT) void k_pscan_b(const int* __restrict__ tot,
                                                  int* __restrict__ bbase, int E)
{
    __shared__ int s[NBKT];
    int b = threadIdx.x;
    int v = tot[b];
    s[b] = v;
    __syncthreads();
    for (int d = 1; d < NBKT; d <<= 1) {
        int u = (b >= d) ? s[b - d] : 0;
        __syncthreads();
        s[b] += u;
        __syncthreads();
    }
    bbase[b] = s[b] - v;
    if (b == NBKT - 1) bbase[NBKT] = E;
}

// ---------------- partition pass 2 (+ bucket-base add): scatter packed records
__global__ __launch_bounds__(256) void k_part2(const int* __restrict__ src,
                                               const int* __restrict__ dst,
                                               const int* __restrict__ hist,
                                               const int* __restrict__ bbase,
                                               unsigned* __restrict__ ebuf, int E, int npb)
{
    __shared__ int cur[NBKT];
    int w = blockIdx.x, NW = gridDim.x;
    for (int i = threadIdx.x; i < NBKT; i += 256)
        cur[i] = hist[i * NW + w] + bbase[i];
    __syncthreads();
    int per = (E + NW - 1) / NW;
    int e0 = w * per, e1 = min(E, e0 + per);
    for (int e = e0 + threadIdx.x; e < e1; e += 256) {
        int d = dst[e], b = d / npb;
        int pos = atomicAdd(&cur[b], 1);
        ebuf[pos] = ((unsigned)src[e] << 7) | (unsigned)(d - b * npb);
    }
}

// ---------------- fused per-bucket: degree count -> LDS scan -> offs -> perm scatter
__global__ __launch_bounds__(256) void k_bucket(const unsigned* __restrict__ ebuf,
                                                const int* __restrict__ bbase,
                                                int* __restrict__ offs,
                                                int* __restrict__ perm,
                                                int N, int npb, int E)
{
    __shared__ int lc[128];
    __shared__ int ls[128];
    int b   = blockIdx.x;
    int tid = threadIdx.x;
    for (int i = tid; i < 128; i += 256) lc[i] = 0;
    __syncthreads();
    int e0 = bbase[b], e1 = bbase[b + 1];
    for (int e = e0 + tid; e < e1; e += 256)
        atomicAdd(&lc[ebuf[e] & 127], 1);
    __syncthreads();
    if (tid < 128) ls[tid] = lc[tid];
    __syncthreads();
    for (int d = 1; d < 128; d <<= 1) {
        int u = (tid < 128 && tid >= d) ? ls[tid - d] : 0;
        __syncthreads();
        if (tid < 128) ls[tid] += u;
        __syncthreads();
    }
    int n0 = b * npb;
    if (tid < 128) {
        int excl = ls[tid] - lc[tid] + e0;
        if (tid < npb && n0 + tid < N) offs[n0 + tid] = excl;
        lc[tid] = excl;
    }
    if (b == 0 && tid == 0) offs[N] = E;
    __syncthreads();
    for (int e = e0 + tid; e < e1; e += 256) {
        unsigned r = ebuf[e];
        int pos = atomicAdd(&lc[r & 127], 1);
        perm[pos] = (int)(r >> 7);
    }
}

// ---------------- per-dst-node aggregation, 16-lane group per node (4 nodes/wave)
__global__ __launch_bounds__(256) void k_aggr(const unsigned short* __restrict__ msgb,
                                              const float* __restrict__ proj,
                                              const int* __restrict__ offs,
                                              const int* __restrict__ perm,
                                              const float* __restrict__ ba1,
                                              const float* __restrict__ ba2,
                                              const float* __restrict__ ba3,
                                              unsigned short* __restrict__ hneigh, int N)
{
    int tid  = threadIdx.x;
    int lane = tid & 63;
    int l    = lane & 15;
    int g    = lane >> 4;
    int wvid = blockIdx.x * (blockDim.x >> 6) + (tid >> 6);
    int n    = wvid * 4 + g;
    bool alive = (n < N);

    int o0 = 0, o1 = 0;
    float dd1 = 0.f, dd2 = 0.f, dd3 = 0.f;
    if (alive) {
        o0 = offs[n];
        o1 = offs[n + 1];
        dd1 = proj[(size_t)n * 8 + 4];
        dd2 = proj[(size_t)n * 8 + 5];
        dd3 = proj[(size_t)n * 8 + 6];
    }
    int deg = o1 - o0;
    float b1 = ba1[0], b2 = ba2[0], b3 = ba3[0];

    int   m0 = min(deg, 16);
    int   sc = 0;
    float a1c = 0.f, a2c = 0.f, a3c = 0.f;
    if (l < m0) {
        sc = perm[o0 + l];
        float4 sp = *(const float4*)(proj + (size_t)sc * 8);
        a1c = __expf(fmaxf(sp.x + dd1 + b1, 0.f));
        a2c = __expf(fmaxf(sp.y + dd2 + b2, 0.f));
        a3c = __expf(fmaxf(sp.z + dd3 + b3, 0.f));
    }
    float s1 = a1c, s2 = a2c, s3 = a3c;
    for (int i = o0 + 16 + l; i < o1; i += 16) {
        int s = perm[i];
        float4 sp = *(const float4*)(proj + (size_t)s * 8);
        s1 += __expf(fmaxf(sp.x + dd1 + b1, 0.f));
        s2 += __expf(fmaxf(sp.y + dd2 + b2, 0.f));
        s3 += __expf(fmaxf(sp.z + dd3 + b3, 0.f));
    }
#pragma unroll
    for (int m = 1; m < 16; m <<= 1) {
        s1 += __shfl_xor(s1, m);
        s2 += __shfl_xor(s2, m);
        s3 += __shfl_xor(s3, m);
    }
    float r1 = 1.f / s1, r2 = 1.f / s2, r3 = 1.f / s3;

    float acc[8] = {};
    int gbase = g << 4;
    {
        float wv = (a1c * r1 + a2c * r2 + a3c * r3) * (1.f / 3.f);
        for (int j = 0; j < m0; ++j) {
            int   s = __shfl(sc, gbase + j);
            float w = __shfl(wv, gbase + j);
            s8v v = *(const s8v*)(msgb + (size_t)s * NDIM + l * 8);
#pragma unroll
            for (int k = 0; k < 8; ++k)
                acc[k] += w * bf2f((unsigned short)v[k]);
        }
    }
    for (int base = o0 + 16; base < o1; base += 16) {
        int m  = min(16, o1 - base);
        int sv = 0;
        float wv = 0.f;
        if (l < m) {
            sv = perm[base + l];
            float4 sp = *(const float4*)(proj + (size_t)sv * 8);
            float a1 = __expf(fmaxf(sp.x + dd1 + b1, 0.f));
            float a2 = __expf(fmaxf(sp.y + dd2 + b2, 0.f));
            float a3 = __expf(fmaxf(sp.z + dd3 + b3, 0.f));
            wv = (a1 * r1 + a2 * r2 + a3 * r3) * (1.f / 3.f);
        }
        for (int j = 0; j < m; ++j) {
            int   s = __shfl(sv, gbase + j);
            float w = __shfl(wv, gbase + j);
            s8v v = *(const s8v*)(msgb + (size_t)s * NDIM + l * 8);
#pragma unroll
            for (int k = 0; k < 8; ++k)
                acc[k] += w * bf2f((unsigned short)v[k]);
        }
    }
    if (alive) {
        float inv = (deg > 0) ? 1.f / (float)deg : 0.f;
        s8v hv;
#pragma unroll
        for (int k = 0; k < 8; ++k)
            hv[k] = (short)f2bf_rne(acc[k] * inv);
        *(s8v*)(hneigh + (size_t)n * NDIM + l * 8) = hv;
    }
}

// ---------------- weight convert: W[k][c] fp32 -> SINGLE bf16 plane (RNE),
// fragment order: offset = ((ct*4+ks)*64 + lane)*8 + j
// col = ct*16 + (lane&15), k = ks*32 + (lane>>4)*8 + j. 32 KB per matrix.
__global__ void k_cvt_w(const float* __restrict__ w0, const float* __restrict__ w1,
                        const float* __restrict__ w2, const float* __restrict__ w3,
                        const float* __restrict__ w4, const float* __restrict__ w5,
                        unsigned short* __restrict__ out)
{
    const float* srcs[6] = {w0, w1, w2, w3, w4, w5};
    const float* W = srcs[blockIdx.y];
    int idx  = blockIdx.x * 256 + threadIdx.x;   // 0..16383
    int j    = idx & 7;
    int lane = (idx >> 3) & 63;
    int ks   = (idx >> 9) & 3;
    int ct   = idx >> 11;
    int col  = ct * 16 + (lane & 15);
    int k    = ks * 32 + (lane >> 4) * 8 + j;
    out[(size_t)blockIdx.y * 16384 + idx] = f2bf_rne(W[k * 128 + col]);
}

// ======== single-plane bf16 GEMM blocks: BM=64, 8 waves = 2rw x 4cw, 32x32/wave.
// Weights read per-MFMA from L2 (fragment-ordered, 8 x 16B loads per pass/wave).

__device__ inline void g_pass_global(const unsigned short* __restrict__ A, int N, int row0,
                                     int ln, int g, int lane, int cw,
                                     const unsigned short* __restrict__ wf, f4v acc[2][2])
{
#pragma unroll
    for (int ks = 0; ks < 4; ++ks) {
        s8v a[2];
#pragma unroll
        for (int fr = 0; fr < 2; ++fr) {
            int rA = min(row0 + fr * 16 + ln, N - 1);
            a[fr] = *(const s8v*)(A + (size_t)rA * 128 + ks * 32 + g * 8);
        }
#pragma unroll
        for (int ct2 = 0; ct2 < 2; ++ct2) {
            int ct = cw * 2 + ct2;
            s8v wv = *(const s8v*)(wf + ((((ct << 2) + ks) * 64) + lane) * 8);
#pragma unroll
            for (int fr = 0; fr < 2; ++fr)
                acc[fr][ct2] = __builtin_amdgcn_mfma_f32_16x16x32_bf16(a[fr], wv, acc[fr][ct2], 0, 0, 0);
        }
    }
}

__device__ inline void g_pass_lds(const unsigned short* __restrict__ act,
                                  int rw, int ln, int g, int lane, int cw,
                                  const unsigned short* __restrict__ wf, f4v acc[2][2])
{
#pragma unroll
    for (int ks = 0; ks < 4; ++ks) {
        s8v a[2];
#pragma unroll
        for (int fr = 0; fr < 2; ++fr) {
            int rl = rw * 32 + fr * 16 + ln;
            a[fr] = *(const s8v*)(&act[(rl * 128 + ks * 32 + g * 8) ^ ((ln & 7) << 3)]);
        }
#pragma unroll
        for (int ct2 = 0; ct2 < 2; ++ct2) {
            int ct = cw * 2 + ct2;
            s8v wv = *(const s8v*)(wf + ((((ct << 2) + ks) * 64) + lane) * 8);
#pragma unroll
            for (int fr = 0; fr < 2; ++fr)
                acc[fr][ct2] = __builtin_amdgcn_mfma_f32_16x16x32_bf16(a[fr], wv, acc[fr][ct2], 0, 0, 0);
        }
    }
}

// bias + relu + bf16 round -> swizzled act LDS; zeros acc
__device__ inline void write_act(f4v acc[2][2], const float* __restrict__ bias,
                                 unsigned short* __restrict__ act,
                                 int rw, int cw, int ln, int g)
{
#pragma unroll
    for (int ct2 = 0; ct2 < 2; ++ct2) {
        int col = (cw * 2 + ct2) * 16 + ln;
        float bv = bias[col];
#pragma unroll
        for (int fr = 0; fr < 2; ++fr) {
#pragma unroll
            for (int q = 0; q < 4; ++q) {
                int rl = rw * 32 + fr * 16 + g * 4 + q;
                float o = fmaxf(acc[fr][ct2][q] + bv, 0.f);
                act[(rl * 128 + col) ^ ((rl & 7) << 3)] = f2bf_rne(o);
                acc[fr][ct2][q] = 0.f;
            }
        }
    }
}

// ---------------- fused 3-layer message MLP (all bf16, single-plane weights)
__global__ __launch_bounds__(512) void k_mlp3(const unsigned short* __restrict__ hb,
                                              const unsigned short* __restrict__ w1,
                                              const unsigned short* __restrict__ w2,
                                              const unsigned short* __restrict__ w3,
                                              const float* __restrict__ b1,
                                              const float* __restrict__ b2,
                                              const float* __restrict__ b3,
                                              unsigned short* __restrict__ msg, int N)
{
    __shared__ unsigned short act0[8192];
    __shared__ unsigned short act1[8192];
    int tid  = threadIdx.x;
    int lane = tid & 63;
    int wid  = tid >> 6;
    int rw   = wid >> 2;
    int cw   = wid & 3;
    int ln   = lane & 15;
    int g    = lane >> 4;
    int row0 = blockIdx.x * 64 + rw * 32;

    f4v acc[2][2] = {};
    g_pass_global(hb, N, row0, ln, g, lane, cw, w1, acc);
    write_act(acc, b1, act0, rw, cw, ln, g);
    __syncthreads();
    g_pass_lds(act0, rw, ln, g, lane, cw, w2, acc);
    write_act(acc, b2, act1, rw, cw, ln, g);
    __syncthreads();
    g_pass_lds(act1, rw, ln, g, lane, cw, w3, acc);
    write_act(acc, b3, act0, rw, cw, ln, g);
    __syncthreads();
    // coalesced copyout
#pragma unroll
    for (int i = 0; i < 2; ++i) {
        int id  = tid + 512 * i;
        int row = id >> 4;
        int c8  = (id & 15) * 8;
        int grow = blockIdx.x * 64 + row;
        if (grow < N) {
            s8v v = *(const s8v*)(&act0[(row * 128 + c8) ^ ((row & 7) << 3)]);
            *(s8v*)(msg + (size_t)grow * 128 + c8) = v;
        }
    }
}

// ---------------- fused head: out = relu(hb@Wc1a + hneigh@Wc1b + bc1) @ Wc2 + bc2
__global__ __launch_bounds__(512) void k_head(const unsigned short* __restrict__ hb,
                                              const unsigned short* __restrict__ hneigh,
                                              const unsigned short* __restrict__ wc1a,
                                              const unsigned short* __restrict__ wc1b,
                                              const unsigned short* __restrict__ wc2,
                                              const float* __restrict__ bc1,
                                              const float* __restrict__ bc2,
                                              float* __restrict__ out, int N)
{
    __shared__ unsigned short act0[8192];
    int tid  = threadIdx.x;
    int lane = tid & 63;
    int wid  = tid >> 6;
    int rw   = wid >> 2;
    int cw   = wid & 3;
    int ln   = lane & 15;
    int g    = lane >> 4;
    int row0 = blockIdx.x * 64 + rw * 32;

    f4v acc[2][2] = {};
    g_pass_global(hb, N, row0, ln, g, lane, cw, wc1a, acc);
    g_pass_global(hneigh, N, row0, ln, g, lane, cw, wc1b, acc);
    write_act(acc, bc1, act0, rw, cw, ln, g);
    __syncthreads();
    g_pass_lds(act0, rw, ln, g, lane, cw, wc2, acc);
    // epilogue: fp32 global store
#pragma unroll
    for (int ct2 = 0; ct2 < 2; ++ct2) {
        int col = (cw * 2 + ct2) * 16 + ln;
        float bv = bc2[col];
#pragma unroll
        for (int fr = 0; fr < 2; ++fr) {
#pragma unroll
            for (int q = 0; q < 4; ++q) {
                int orow = row0 + fr * 16 + g * 4 + q;
                if (orow < N)
                    out[(size_t)orow * 128 + col] = acc[fr][ct2][q] + bv;
            }
        }
    }
}

extern "C" void kernel_launch(void* const* d_in, const int* in_sizes, int n_in,
                              void* d_out, int out_size, void* d_ws, size_t ws_size,
                              hipStream_t stream)
{
    const float* h   = (const float*)d_in[0];
    const int*   src = (const int*)d_in[1];
    const int*   dst = (const int*)d_in[2];
    const float* Wm1 = (const float*)d_in[3];
    const float* bm1 = (const float*)d_in[4];
    const float* Wm2 = (const float*)d_in[5];
    const float* bm2 = (const float*)d_in[6];
    const float* Wm3 = (const float*)d_in[7];
    const float* bm3 = (const float*)d_in[8];
    const float* Wa1 = (const float*)d_in[9];
    const float* ba1 = (const float*)d_in[10];
    const float* Wa2 = (const float*)d_in[11];
    const float* ba2 = (const float*)d_in[12];
    const float* Wa3 = (const float*)d_in[13];
    const float* ba3 = (const float*)d_in[14];
    const float* Wc1 = (const float*)d_in[15];
    const float* bc1 = (const float*)d_in[16];
    const float* Wc2 = (const float*)d_in[17];
    const float* bc2 = (const float*)d_in[18];

    const int N = in_sizes[0] / NDIM;
    const int E = in_sizes[1];
    const int npb = (N + NBKT - 1) / NBKT;
    float* out = (float*)d_out;

    // workspace layout
    unsigned short* wt  = (unsigned short*)d_ws;                 // 6*16384 ushorts (192 KB)
    unsigned short* hb  = wt + 6 * 16384;                        // N*128 bf16 (h cast)
    unsigned short* mb1 = hb + (size_t)N * NDIM;                 // N*128 bf16 (hneigh)
    unsigned short* mb2 = mb1 + (size_t)N * NDIM;                // N*128 bf16 (msg)
    float* proj = (float*)(mb2 + (size_t)N * NDIM);              // N*8
    int* offs   = (int*)(proj + (size_t)N * 8);                  // N+1
    int* hist   = offs + N + 1;                                  // NBKT*NWPART
    int* bbase  = hist + NBKT * NWPART;                          // NBKT+1
    int* btot   = bbase + NBKT + 1;                              // NBKT
    unsigned* ebuf = (unsigned*)(btot + NBKT);                   // E
    int* perm   = (int*)(ebuf + E);                              // E

    const unsigned short* wt_m1  = wt;
    const unsigned short* wt_m2  = wt + 1 * 16384;
    const unsigned short* wt_m3  = wt + 2 * 16384;
    const unsigned short* wt_c1a = wt + 3 * 16384;
    const unsigned short* wt_c1b = wt + 4 * 16384;
    const unsigned short* wt_c2  = wt + 5 * 16384;

    k_cvt_w<<<dim3(64, 6), 256, 0, stream>>>(Wm1, Wm2, Wm3, Wc1, Wc1 + 128 * 128, Wc2, wt);
    k_proj<<<(N + 15) / 16, 256, 0, stream>>>(h, Wa1, Wa2, Wa3, proj, hb, N);

    // ---- bucketed CSR build
    k_part1<<<NWPART, 256, 0, stream>>>(dst, hist, E, npb);
    k_pscan_a<<<NBKT, NWPART, 0, stream>>>(hist, btot);
    k_pscan_b<<<1, NBKT, 0, stream>>>(btot, bbase, E);
    k_part2<<<NWPART, 256, 0, stream>>>(src, dst, hist, bbase, ebuf, E, npb);
    k_bucket<<<NBKT, 256, 0, stream>>>(ebuf, bbase, offs, perm, N, npb, E);

    int gb = (N + 63) / 64;
    // fused 3-layer message MLP -> msg (mb2)
    k_mlp3<<<gb, 512, 0, stream>>>(hb, wt_m1, wt_m2, wt_m3, bm1, bm2, bm3, mb2, N);

    // aggregation -> hneigh (mb1)
    int nwaves = (N + 3) / 4;
    int nblk   = (nwaves + 3) / 4;
    k_aggr<<<nblk, 256, 0, stream>>>(mb2, proj, offs, perm, ba1, ba2, ba3, mb1, N);

    // fused head -> out
    k_head<<<gb, 512, 0, stream>>>(hb, mb1, wt_c1a, wt_c1b, wt_c2, bc1, bc2, out, N);
}

// Round 15
// 108.665 us; speedup vs baseline: 1.6998x; 1.2961x over previous
//
#include <hip/hip_runtime.h>

#define NDIM 128
#define NBKT 512      // dst buckets for CSR build
#define NWPART 128    // partition workgroups

typedef __attribute__((ext_vector_type(8))) short s8v;   // 8 bf16 in 4 VGPRs
typedef __attribute__((ext_vector_type(4))) float f4v;   // MFMA accumulator

__device__ inline unsigned short f2bf_rne(float x) {
    unsigned u = __float_as_uint(x);
    unsigned r = u + 0x7FFFu + ((u >> 16) & 1u);
    return (unsigned short)(r >> 16);
}
__device__ inline float bf2f(unsigned short b) {
    return __uint_as_float(((unsigned)b) << 16);
}

// ================= K1: fused weight-convert + proj/hb + part1 histogram ========
__global__ __launch_bounds__(256) void k_front(const float* __restrict__ h,
                                               const float* __restrict__ Wa1,
                                               const float* __restrict__ Wa2,
                                               const float* __restrict__ Wa3,
                                               float* __restrict__ proj,
                                               unsigned short* __restrict__ hb,
                                               const float* __restrict__ w0,
                                               const float* __restrict__ w1,
                                               const float* __restrict__ w2,
                                               const float* __restrict__ w3,
                                               const float* __restrict__ w4,
                                               const float* __restrict__ w5,
                                               unsigned short* __restrict__ wtout,
                                               const int* __restrict__ dst,
                                               int* __restrict__ hist,
                                               int N, int E, int npb)
{
    __shared__ int lh[NBKT];
    int tid = threadIdx.x;
    int nbProj = (N + 15) >> 4;
    int bid = blockIdx.x;

    if (bid < 384) {
        // ---- weight convert: single bf16 plane, fragment order
        const float* srcs[6] = {w0, w1, w2, w3, w4, w5};
        int mat = bid >> 6;
        int idx = (bid & 63) * 256 + tid;    // 0..16383
        int j    = idx & 7;
        int lane = (idx >> 3) & 63;
        int ks   = (idx >> 9) & 3;
        int ct   = idx >> 11;
        int col  = ct * 16 + (lane & 15);
        int k    = ks * 32 + (lane >> 4) * 8 + j;
        wtout[(size_t)mat * 16384 + idx] = f2bf_rne(srcs[mat][k * 128 + col]);
        return;
    }
    bid -= 384;
    if (bid < nbProj) {
        // ---- proj + bf16 cast of h (16-lane group per node)
        int l = tid & 15;
        int n = bid * 16 + (tid >> 4);
        if (n >= N) return;
        int o = l * 8;
        float4 w1s0 = *(const float4*)(Wa1 + o),       w1s1 = *(const float4*)(Wa1 + o + 4);
        float4 w1d0 = *(const float4*)(Wa1 + 128 + o), w1d1 = *(const float4*)(Wa1 + 132 + o);
        float4 w2s0 = *(const float4*)(Wa2 + o),       w2s1 = *(const float4*)(Wa2 + o + 4);
        float4 w2d0 = *(const float4*)(Wa2 + 128 + o), w2d1 = *(const float4*)(Wa2 + 132 + o);
        float4 w3s0 = *(const float4*)(Wa3 + o),       w3s1 = *(const float4*)(Wa3 + o + 4);
        float4 w3d0 = *(const float4*)(Wa3 + 128 + o), w3d1 = *(const float4*)(Wa3 + 132 + o);
        float4 x0 = *(const float4*)(h + (size_t)n * NDIM + o);
        float4 x1 = *(const float4*)(h + (size_t)n * NDIM + o + 4);
        {
            s8v hv;
            hv[0] = (short)f2bf_rne(x0.x); hv[1] = (short)f2bf_rne(x0.y);
            hv[2] = (short)f2bf_rne(x0.z); hv[3] = (short)f2bf_rne(x0.w);
            hv[4] = (short)f2bf_rne(x1.x); hv[5] = (short)f2bf_rne(x1.y);
            hv[6] = (short)f2bf_rne(x1.z); hv[7] = (short)f2bf_rne(x1.w);
            *(s8v*)(hb + (size_t)n * NDIM + o) = hv;
        }
        float s1 = x0.x*w1s0.x + x0.y*w1s0.y + x0.z*w1s0.z + x0.w*w1s0.w
                 + x1.x*w1s1.x + x1.y*w1s1.y + x1.z*w1s1.z + x1.w*w1s1.w;
        float s2 = x0.x*w2s0.x + x0.y*w2s0.y + x0.z*w2s0.z + x0.w*w2s0.w
                 + x1.x*w2s1.x + x1.y*w2s1.y + x1.z*w2s1.z + x1.w*w2s1.w;
        float s3 = x0.x*w3s0.x + x0.y*w3s0.y + x0.z*w3s0.z + x0.w*w3s0.w
                 + x1.x*w3s1.x + x1.y*w3s1.y + x1.z*w3s1.z + x1.w*w3s1.w;
        float d1 = x0.x*w1d0.x + x0.y*w1d0.y + x0.z*w1d0.z + x0.w*w1d0.w
                 + x1.x*w1d1.x + x1.y*w1d1.y + x1.z*w1d1.z + x1.w*w1d1.w;
        float d2 = x0.x*w2d0.x + x0.y*w2d0.y + x0.z*w2d0.z + x0.w*w2d0.w
                 + x1.x*w2d1.x + x1.y*w2d1.y + x1.z*w2d1.z + x1.w*w2d1.w;
        float d3 = x0.x*w3d0.x + x0.y*w3d0.y + x0.z*w3d0.z + x0.w*w3d0.w
                 + x1.x*w3d1.x + x1.y*w3d1.y + x1.z*w3d1.z + x1.w*w3d1.w;
#pragma unroll
        for (int m = 1; m < 16; m <<= 1) {
            s1 += __shfl_xor(s1, m);
            s2 += __shfl_xor(s2, m);
            s3 += __shfl_xor(s3, m);
            d1 += __shfl_xor(d1, m);
            d2 += __shfl_xor(d2, m);
            d3 += __shfl_xor(d3, m);
        }
        if (l == 0) {
            *(float4*)(proj + (size_t)n * 8)     = make_float4(s1, s2, s3, 0.f);
            *(float4*)(proj + (size_t)n * 8 + 4) = make_float4(d1, d2, d3, 0.f);
        }
        return;
    }
    bid -= nbProj;
    // ---- part1: per-(wg,bucket) histogram
    {
        int w = bid, NW = NWPART;
        for (int i = tid; i < NBKT; i += 256) lh[i] = 0;
        __syncthreads();
        int per = (E + NW - 1) / NW;
        int e0 = w * per, e1 = min(E, e0 + per);
        for (int e = e0 + tid; e < e1; e += 256)
            atomicAdd(&lh[dst[e] / npb], 1);
        __syncthreads();
        for (int b = tid; b < NBKT; b += 256)
            hist[b * NW + w] = lh[b];
    }
}

// ---------------- partition scan, parallelized
__global__ __launch_bounds__(NWPART) void k_pscan_a(int* __restrict__ hist,
                                                    int* __restrict__ tot)
{
    __shared__ int s[NWPART];
    int b = blockIdx.x, t = threadIdx.x;
    int v = hist[b * NWPART + t];
    s[t] = v;
    __syncthreads();
    for (int d = 1; d < NWPART; d <<= 1) {
        int u = (t >= d) ? s[t - d] : 0;
        __syncthreads();
        s[t] += u;
        __syncthreads();
    }
    hist[b * NWPART + t] = s[t] - v;
    if (t == NWPART - 1) tot[b] = s[NWPART - 1];
}

__global__ __launch_bounds__(NBKT) void k_pscan_b(const int* __restrict__ tot,
                                                  int* __restrict__ bbase, int E)
{
    __shared__ int s[NBKT];
    int b = threadIdx.x;
    int v = tot[b];
    s[b] = v;
    __syncthreads();
    for (int d = 1; d < NBKT; d <<= 1) {
        int u = (b >= d) ? s[b - d] : 0;
        __syncthreads();
        s[b] += u;
        __syncthreads();
    }
    bbase[b] = s[b] - v;
    if (b == NBKT - 1) bbase[NBKT] = E;
}

// ======== single-plane bf16 GEMM helpers (BM=64, 8 waves = 2rw x 4cw) ========

__device__ inline void g_pass_global(const unsigned short* __restrict__ A, int N, int row0,
                                     int ln, int g, int lane, int cw,
                                     const unsigned short* __restrict__ wf, f4v acc[2][2])
{
#pragma unroll
    for (int ks = 0; ks < 4; ++ks) {
        s8v a[2];
#pragma unroll
        for (int fr = 0; fr < 2; ++fr) {
            int rA = min(row0 + fr * 16 + ln, N - 1);
            a[fr] = *(const s8v*)(A + (size_t)rA * 128 + ks * 32 + g * 8);
        }
#pragma unroll
        for (int ct2 = 0; ct2 < 2; ++ct2) {
            int ct = cw * 2 + ct2;
            s8v wv = *(const s8v*)(wf + ((((ct << 2) + ks) * 64) + lane) * 8);
#pragma unroll
            for (int fr = 0; fr < 2; ++fr)
                acc[fr][ct2] = __builtin_amdgcn_mfma_f32_16x16x32_bf16(a[fr], wv, acc[fr][ct2], 0, 0, 0);
        }
    }
}

__device__ inline void g_pass_lds(const unsigned short* __restrict__ act,
                                  int rw, int ln, int g, int lane, int cw,
                                  const unsigned short* __restrict__ wf, f4v acc[2][2])
{
#pragma unroll
    for (int ks = 0; ks < 4; ++ks) {
        s8v a[2];
#pragma unroll
        for (int fr = 0; fr < 2; ++fr) {
            int rl = rw * 32 + fr * 16 + ln;
            a[fr] = *(const s8v*)(&act[(rl * 128 + ks * 32 + g * 8) ^ ((ln & 7) << 3)]);
        }
#pragma unroll
        for (int ct2 = 0; ct2 < 2; ++ct2) {
            int ct = cw * 2 + ct2;
            s8v wv = *(const s8v*)(wf + ((((ct << 2) + ks) * 64) + lane) * 8);
#pragma unroll
            for (int fr = 0; fr < 2; ++fr)
                acc[fr][ct2] = __builtin_amdgcn_mfma_f32_16x16x32_bf16(a[fr], wv, acc[fr][ct2], 0, 0, 0);
        }
    }
}

__device__ inline void write_act(f4v acc[2][2], const float* __restrict__ bias,
                                 unsigned short* __restrict__ act,
                                 int rw, int cw, int ln, int g)
{
#pragma unroll
    for (int ct2 = 0; ct2 < 2; ++ct2) {
        int col = (cw * 2 + ct2) * 16 + ln;
        float bv = bias[col];
#pragma unroll
        for (int fr = 0; fr < 2; ++fr) {
#pragma unroll
            for (int q = 0; q < 4; ++q) {
                int rl = rw * 32 + fr * 16 + g * 4 + q;
                float o = fmaxf(acc[fr][ct2][q] + bv, 0.f);
                act[(rl * 128 + col) ^ ((rl & 7) << 3)] = f2bf_rne(o);
                acc[fr][ct2][q] = 0.f;
            }
        }
    }
}

// ================= K4: fused part2 scatter + 3-layer message MLP =============
__global__ __launch_bounds__(512) void k_mid(const int* __restrict__ src,
                                             const int* __restrict__ dst,
                                             const int* __restrict__ hist,
                                             const int* __restrict__ bbase,
                                             unsigned* __restrict__ ebuf,
                                             int E, int npb,
                                             const unsigned short* __restrict__ hb,
                                             const unsigned short* __restrict__ w1,
                                             const unsigned short* __restrict__ w2,
                                             const unsigned short* __restrict__ w3,
                                             const float* __restrict__ b1,
                                             const float* __restrict__ b2,
                                             const float* __restrict__ b3,
                                             unsigned short* __restrict__ msg, int N)
{
    __shared__ int cur[NBKT];
    __shared__ unsigned short act0[8192];
    __shared__ unsigned short act1[8192];
    int tid = threadIdx.x;

    if (blockIdx.x < NWPART) {
        // ---- part2: scatter packed (src<<7|ldst) into bucket-grouped ebuf
        int w = blockIdx.x, NW = NWPART;
        for (int i = tid; i < NBKT; i += 512)
            cur[i] = hist[i * NW + w] + bbase[i];
        __syncthreads();
        int per = (E + NW - 1) / NW;
        int e0 = w * per, e1 = min(E, e0 + per);
        for (int e = e0 + tid; e < e1; e += 512) {
            int d = dst[e], b = d / npb;
            int pos = atomicAdd(&cur[b], 1);
            ebuf[pos] = ((unsigned)src[e] << 7) | (unsigned)(d - b * npb);
        }
        return;
    }
    // ---- mlp3
    int mb   = blockIdx.x - NWPART;
    int lane = tid & 63;
    int wid  = tid >> 6;
    int rw   = wid >> 2;
    int cw   = wid & 3;
    int ln   = lane & 15;
    int g    = lane >> 4;
    int row0 = mb * 64 + rw * 32;

    f4v acc[2][2] = {};
    g_pass_global(hb, N, row0, ln, g, lane, cw, w1, acc);
    write_act(acc, b1, act0, rw, cw, ln, g);
    __syncthreads();
    g_pass_lds(act0, rw, ln, g, lane, cw, w2, acc);
    write_act(acc, b2, act1, rw, cw, ln, g);
    __syncthreads();
    g_pass_lds(act1, rw, ln, g, lane, cw, w3, acc);
    write_act(acc, b3, act0, rw, cw, ln, g);
    __syncthreads();
#pragma unroll
    for (int i = 0; i < 2; ++i) {
        int id  = tid + 512 * i;
        int row = id >> 4;
        int c8  = (id & 15) * 8;
        int grow = mb * 64 + row;
        if (grow < N) {
            s8v v = *(const s8v*)(&act0[(row * 128 + c8) ^ ((row & 7) << 3)]);
            *(s8v*)(msg + (size_t)grow * 128 + c8) = v;
        }
    }
}

// ---------------- fused per-bucket: degree count -> LDS scan -> offs -> perm scatter
__global__ __launch_bounds__(256) void k_bucket(const unsigned* __restrict__ ebuf,
                                                const int* __restrict__ bbase,
                                                int* __restrict__ offs,
                                                int* __restrict__ perm,
                                                int N, int npb, int E)
{
    __shared__ int lc[128];
    __shared__ int ls[128];
    int b   = blockIdx.x;
    int tid = threadIdx.x;
    for (int i = tid; i < 128; i += 256) lc[i] = 0;
    __syncthreads();
    int e0 = bbase[b], e1 = bbase[b + 1];
    for (int e = e0 + tid; e < e1; e += 256)
        atomicAdd(&lc[ebuf[e] & 127], 1);
    __syncthreads();
    if (tid < 128) ls[tid] = lc[tid];
    __syncthreads();
    for (int d = 1; d < 128; d <<= 1) {
        int u = (tid < 128 && tid >= d) ? ls[tid - d] : 0;
        __syncthreads();
        if (tid < 128) ls[tid] += u;
        __syncthreads();
    }
    int n0 = b * npb;
    if (tid < 128) {
        int excl = ls[tid] - lc[tid] + e0;
        if (tid < npb && n0 + tid < N) offs[n0 + tid] = excl;
        lc[tid] = excl;
    }
    if (b == 0 && tid == 0) offs[N] = E;
    __syncthreads();
    for (int e = e0 + tid; e < e1; e += 256) {
        unsigned r = ebuf[e];
        int pos = atomicAdd(&lc[r & 127], 1);
        perm[pos] = (int)(r >> 7);
    }
}

// ================= K6: fused aggregation + head =============================
// Phase A: 64 nodes aggregated into LDS hn (16-lane group per node, 2 rounds).
// Phase B: out = relu(hb@Wc1a + hn@Wc1b + bc1) @ Wc2 + bc2.
__global__ __launch_bounds__(512) void k_tail(const unsigned short* __restrict__ hb,
                                              const unsigned short* __restrict__ msgb,
                                              const float* __restrict__ proj,
                                              const int* __restrict__ offs,
                                              const int* __restrict__ perm,
                                              const float* __restrict__ ba1,
                                              const float* __restrict__ ba2,
                                              const float* __restrict__ ba3,
                                              const unsigned short* __restrict__ wc1a,
                                              const unsigned short* __restrict__ wc1b,
                                              const unsigned short* __restrict__ wc2,
                                              const float* __restrict__ bc1,
                                              const float* __restrict__ bc2,
                                              float* __restrict__ out, int N)
{
    __shared__ unsigned short hn[8192];
    __shared__ unsigned short act0[8192];
    int tid  = threadIdx.x;
    int lane = tid & 63;
    int l    = lane & 15;
    int grp  = lane >> 4;      // 0..3 within wave
    int wv   = tid >> 6;       // 0..7
    int r0   = blockIdx.x * 64;
    float b1 = ba1[0], b2 = ba2[0], b3 = ba3[0];

    // ---- Phase A: aggregation into hn LDS
    for (int rnd = 0; rnd < 2; ++rnd) {
        int rl = rnd * 32 + wv * 4 + grp;
        int n  = r0 + rl;
        bool alive = (n < N);
        int o0 = 0, o1 = 0;
        float dd1 = 0.f, dd2 = 0.f, dd3 = 0.f;
        if (alive) {
            o0 = offs[n];
            o1 = offs[n + 1];
            dd1 = proj[(size_t)n * 8 + 4];
            dd2 = proj[(size_t)n * 8 + 5];
            dd3 = proj[(size_t)n * 8 + 6];
        }
        int deg = o1 - o0;

        int   m0 = min(deg, 16);
        int   sc = 0;
        float a1c = 0.f, a2c = 0.f, a3c = 0.f;
        if (l < m0) {
            sc = perm[o0 + l];
            float4 sp = *(const float4*)(proj + (size_t)sc * 8);
            a1c = __expf(fmaxf(sp.x + dd1 + b1, 0.f));
            a2c = __expf(fmaxf(sp.y + dd2 + b2, 0.f));
            a3c = __expf(fmaxf(sp.z + dd3 + b3, 0.f));
        }
        float s1 = a1c, s2 = a2c, s3 = a3c;
        for (int i = o0 + 16 + l; i < o1; i += 16) {
            int s = perm[i];
            float4 sp = *(const float4*)(proj + (size_t)s * 8);
            s1 += __expf(fmaxf(sp.x + dd1 + b1, 0.f));
            s2 += __expf(fmaxf(sp.y + dd2 + b2, 0.f));
            s3 += __expf(fmaxf(sp.z + dd3 + b3, 0.f));
        }
#pragma unroll
        for (int m = 1; m < 16; m <<= 1) {
            s1 += __shfl_xor(s1, m);
            s2 += __shfl_xor(s2, m);
            s3 += __shfl_xor(s3, m);
        }
        float r1 = 1.f / s1, r2 = 1.f / s2, r3 = 1.f / s3;

        float acc[8] = {};
        int gbase = grp << 4;
        {
            float wvv = (a1c * r1 + a2c * r2 + a3c * r3) * (1.f / 3.f);
            for (int j = 0; j < m0; ++j) {
                int   s = __shfl(sc, gbase + j);
                float w = __shfl(wvv, gbase + j);
                s8v v = *(const s8v*)(msgb + (size_t)s * NDIM + l * 8);
#pragma unroll
                for (int k = 0; k < 8; ++k)
                    acc[k] += w * bf2f((unsigned short)v[k]);
            }
        }
        for (int base = o0 + 16; base < o1; base += 16) {
            int m  = min(16, o1 - base);
            int sv = 0;
            float wvv = 0.f;
            if (l < m) {
                sv = perm[base + l];
                float4 sp = *(const float4*)(proj + (size_t)sv * 8);
                float a1 = __expf(fmaxf(sp.x + dd1 + b1, 0.f));
                float a2 = __expf(fmaxf(sp.y + dd2 + b2, 0.f));
                float a3 = __expf(fmaxf(sp.z + dd3 + b3, 0.f));
                wvv = (a1 * r1 + a2 * r2 + a3 * r3) * (1.f / 3.f);
            }
            for (int j = 0; j < m; ++j) {
                int   s = __shfl(sv, gbase + j);
                float w = __shfl(wvv, gbase + j);
                s8v v = *(const s8v*)(msgb + (size_t)s * NDIM + l * 8);
#pragma unroll
                for (int k = 0; k < 8; ++k)
                    acc[k] += w * bf2f((unsigned short)v[k]);
            }
        }
        float inv = (alive && deg > 0) ? 1.f / (float)deg : 0.f;
        s8v hv;
#pragma unroll
        for (int k = 0; k < 8; ++k)
            hv[k] = (short)f2bf_rne(acc[k] * inv);
        *(s8v*)(&hn[(rl * 128 + l * 8) ^ ((rl & 7) << 3)]) = hv;
    }
    __syncthreads();

    // ---- Phase B: c1 (hb global + hn LDS) -> act0 -> c2 -> out
    int wid  = tid >> 6;
    int rw   = wid >> 2;
    int cw   = wid & 3;
    int ln   = lane & 15;
    int g    = lane >> 4;
    int row0 = r0 + rw * 32;

    f4v acc2[2][2] = {};
    g_pass_global(hb, N, row0, ln, g, lane, cw, wc1a, acc2);
    g_pass_lds(hn, rw, ln, g, lane, cw, wc1b, acc2);
    write_act(acc2, bc1, act0, rw, cw, ln, g);
    __syncthreads();
    g_pass_lds(act0, rw, ln, g, lane, cw, wc2, acc2);
#pragma unroll
    for (int ct2 = 0; ct2 < 2; ++ct2) {
        int col = (cw * 2 + ct2) * 16 + ln;
        float bv = bc2[col];
#pragma unroll
        for (int fr = 0; fr < 2; ++fr) {
#pragma unroll
            for (int q = 0; q < 4; ++q) {
                int orow = row0 + fr * 16 + g * 4 + q;
                if (orow < N)
                    out[(size_t)orow * 128 + col] = acc2[fr][ct2][q] + bv;
            }
        }
    }
}

extern "C" void kernel_launch(void* const* d_in, const int* in_sizes, int n_in,
                              void* d_out, int out_size, void* d_ws, size_t ws_size,
                              hipStream_t stream)
{
    const float* h   = (const float*)d_in[0];
    const int*   src = (const int*)d_in[1];
    const int*   dst = (const int*)d_in[2];
    const float* Wm1 = (const float*)d_in[3];
    const float* bm1 = (const float*)d_in[4];
    const float* Wm2 = (const float*)d_in[5];
    const float* bm2 = (const float*)d_in[6];
    const float* Wm3 = (const float*)d_in[7];
    const float* bm3 = (const float*)d_in[8];
    const float* Wa1 = (const float*)d_in[9];
    const float* ba1 = (const float*)d_in[10];
    const float* Wa2 = (const float*)d_in[11];
    const float* ba2 = (const float*)d_in[12];
    const float* Wa3 = (const float*)d_in[13];
    const float* ba3 = (const float*)d_in[14];
    const float* Wc1 = (const float*)d_in[15];
    const float* bc1 = (const float*)d_in[16];
    const float* Wc2 = (const float*)d_in[17];
    const float* bc2 = (const float*)d_in[18];

    const int N = in_sizes[0] / NDIM;
    const int E = in_sizes[1];
    const int npb = (N + NBKT - 1) / NBKT;
    float* out = (float*)d_out;

    // workspace layout
    unsigned short* wt  = (unsigned short*)d_ws;                 // 6*16384 ushorts (192 KB)
    unsigned short* hb  = wt + 6 * 16384;                        // N*128 bf16 (h cast)
    unsigned short* mb2 = hb + (size_t)N * NDIM;                 // N*128 bf16 (msg)
    float* proj = (float*)(mb2 + (size_t)N * NDIM);              // N*8
    int* offs   = (int*)(proj + (size_t)N * 8);                  // N+1
    int* hist   = offs + N + 1;                                  // NBKT*NWPART
    int* bbase  = hist + NBKT * NWPART;                          // NBKT+1
    int* btot   = bbase + NBKT + 1;                              // NBKT
    unsigned* ebuf = (unsigned*)(btot + NBKT);                   // E
    int* perm   = (int*)(ebuf + E);                              // E

    const unsigned short* wt_m1  = wt;
    const unsigned short* wt_m2  = wt + 1 * 16384;
    const unsigned short* wt_m3  = wt + 2 * 16384;
    const unsigned short* wt_c1a = wt + 3 * 16384;
    const unsigned short* wt_c1b = wt + 4 * 16384;
    const unsigned short* wt_c2  = wt + 5 * 16384;

    int nbProj = (N + 15) / 16;
    int gb64   = (N + 63) / 64;

    // K1: cvt_w (384) + proj (nbProj) + part1 (NWPART)
    k_front<<<384 + nbProj + NWPART, 256, 0, stream>>>(
        h, Wa1, Wa2, Wa3, proj, hb,
        Wm1, Wm2, Wm3, Wc1, Wc1 + 128 * 128, Wc2, wt,
        dst, hist, N, E, npb);

    // K2/K3: partition scans
    k_pscan_a<<<NBKT, NWPART, 0, stream>>>(hist, btot);
    k_pscan_b<<<1, NBKT, 0, stream>>>(btot, bbase, E);

    // K4: part2 (NWPART) + mlp3 (gb64)
    k_mid<<<NWPART + gb64, 512, 0, stream>>>(
        src, dst, hist, bbase, ebuf, E, npb,
        hb, wt_m1, wt_m2, wt_m3, bm1, bm2, bm3, mb2, N);

    // K5: per-bucket CSR finalize
    k_bucket<<<NBKT, 256, 0, stream>>>(ebuf, bbase, offs, perm, N, npb, E);

    // K6: fused aggregation + head
    k_tail<<<gb64, 512, 0, stream>>>(
        hb, mb2, proj, offs, perm, ba1, ba2, ba3,
        wt_c1a, wt_c1b, wt_c2, bc1, bc2, out, N);
}